// Round 15
// baseline (72.852 us; speedup 1.0000x reference)
//
#include <hip/hip_runtime.h>

// Fused 3D SSIM, window 7^3, VALID. pred/targ: (4,1,32,320,320) f32.
// BARRIER-FREE wave-private structure: block = 16h x 26w output tile; each
// of the 4 waves owns 4 output rows and stages its own 10 input rows
// (rows 4w..4w+9, 16 pair-cols, p/q interleaved float4) into a private LDS
// region, double-buffered. Within-wave DS ordering makes the t-pipeline
// correct with NO __syncthreads in the main loop -> waves drift and overlap
// VMEM/DS/VALU. Per slice: commit s+1 (regs->LDS) | issue loads s+2 |
// colsum (7x ds_read_b128) | DPP row_shr w-gather | packed (E,O) 7-ring |
// packed SSIM. Fields: f0=sum p, f1=sum q, f2=sum p^2+q^2, f3=sum p*q.

#define NPIX 343

constexpr int B = 4, T = 32, H = 320, W = 320;
constexpr int TO = T - 6, HO = H - 6, WO = W - 6;   // 26, 314, 314
constexpr long long NOUT = (long long)B * TO * HO * WO;

constexpr int TH = 16, TW = 26;    // output tile
constexpr int NTH = 20, NTW = 13;  // 20*16 >= 314; 13*26 >= 314

typedef float v2f __attribute__((ext_vector_type(2)));

template<int N>
__device__ __forceinline__ float row_shr(float x) {
    // lane i (within its 16-lane DPP row) receives lane i-N; OOB -> 0
    return __int_as_float(__builtin_amdgcn_update_dpp(
        0, __float_as_int(x), 0x110 | N, 0xF, 0xF, true));
}

__global__ __launch_bounds__(256) void ssim3d_fused(
    const float* __restrict__ pred,
    const float* __restrict__ targ,
    const float* __restrict__ drange,
    double* __restrict__ acc)
{
    __shared__ float4 swv[4][2][10][16];   // 20480 B, wave-private regions
    __shared__ float wsum[4];

    const int bx = blockIdx.x;
    const int b  = bx / (NTH * NTW);
    int rem      = bx % (NTH * NTW);
    const int h0 = (rem / NTW) * TH;
    const int w0 = (rem % NTW) * TW;

    const int tid  = threadIdx.x;
    const int wv   = tid >> 6;    // wave 0..3
    const int lane = tid & 63;
    const int ohl  = lane >> 4;   // 0..3: output row within wave
    const int k    = lane & 15;   // pair-column 0..15
    const int h0w  = h0 + 4 * wv; // wave's first output row

    const float* pb = pred + (long long)b * T * H * W;
    const float* qb = targ + (long long)b * T * H * W;

    // ---- wave-private staging: 160 items = 10 rows x 16 pair-cols ----
    // lane handles items lane, lane+64, (lane<32: lane+128)
    const bool has2 = (lane < 32);
    auto gofs = [&](int i) {
        int r = min(h0w + (i >> 4), H - 1);
        int c = min(w0 + 2 * (i & 15), W - 2);
        return (long long)r * W + c;
    };
    const long long ga0 = gofs(lane);
    const long long ga1 = gofs(lane + 64);
    const long long ga2 = has2 ? gofs(lane + 128) : 0;

    float2 p0, q0, p1, q1, p2, q2;
    auto loadw = [&](int s) {
        const long long so = (long long)s * H * W;
        p0 = *reinterpret_cast<const float2*>(pb + so + ga0);
        q0 = *reinterpret_cast<const float2*>(qb + so + ga0);
        p1 = *reinterpret_cast<const float2*>(pb + so + ga1);
        q1 = *reinterpret_cast<const float2*>(qb + so + ga1);
        if (has2) {
            p2 = *reinterpret_cast<const float2*>(pb + so + ga2);
            q2 = *reinterpret_cast<const float2*>(qb + so + ga2);
        }
    };
    auto commitw = [&](int buf) {
        swv[wv][buf][ohl][k]     = make_float4(p0.x, p0.y, q0.x, q0.y);
        swv[wv][buf][4 + ohl][k] = make_float4(p1.x, p1.y, q1.x, q1.y);
        if (has2)
            swv[wv][buf][8 + ohl][k] = make_float4(p2.x, p2.y, q2.x, q2.y);
    };

    // ---- output mapping: thread k emits local cols 2k-6 (even), 2k-5 (odd)
    const bool vh = (h0w + ohl < HO);
    const bool k3 = (k >= 3);
    const bool vE = k3 && vh && (w0 + 2 * k - 6 < WO);
    const bool vO = k3 && vh && (w0 + 2 * k - 5 < WO);

    const float dr  = drange[b];
    const float C1s = (0.01f * dr) * (0.01f * dr);
    const float C2s = (0.03f * dr) * (0.03f * dr);
    const float inv  = 1.0f / (float)NPIX;
    const float covn = (float)NPIX / (float)(NPIX - 1);
    const v2f invv  = {inv, inv};
    const v2f C1vv  = {C1s, C1s};
    const v2f C2vv  = {C2s, C2s};
    const v2f covnv = {covn, covn};
    const v2f c2cov = {2.f * covn, 2.f * covn};

    v2f rEO[4][7], tEO[4];
#pragma unroll
    for (int f = 0; f < 4; ++f) {
        tEO[f] = (v2f){0.f, 0.f};
#pragma unroll
        for (int j = 0; j < 7; ++j) rEO[f][j] = (v2f){0.f, 0.f};
    }
    float loss = 0.f;

    // ---- one slice; jj and flags compile-time at every call site ----
    auto slice = [&](int s, int jj, bool doEmit, bool doCommit, bool doPrefetch) {
        if (doCommit)  commitw((s + 1) & 1);  // regs loaded at slice s-1
        if (doPrefetch) loadw(s + 2);         // consumed at slice s+1

        // ---- per-thread pair-colsum: cols (2k,2k+1), rows ohl..ohl+6 ----
        const int bs = s & 1;
        v2f c0 = {0.f, 0.f}, c1v = {0.f, 0.f}, c2 = {0.f, 0.f}, c3 = {0.f, 0.f};
#pragma unroll
        for (int dy = 0; dy < 7; ++dy) {
            float4 v = swv[wv][bs][ohl + dy][k];
            v2f vp = {v.x, v.y};
            v2f vq = {v.z, v.w};
            c0 += vp;
            c1v += vq;
            c2 = __builtin_elementwise_fma(vp, vp, c2);
            c2 = __builtin_elementwise_fma(vq, vq, c2);
            c3 = __builtin_elementwise_fma(vp, vq, c3);
        }

        // ---- in-register w-gather via DPP row_shr ----
        v2f sv[4];
        {
            v2f cf[4] = {c0, c1v, c2, c3};
#pragma unroll
            for (int f = 0; f < 4; ++f) {
                float ps = cf[f].x + cf[f].y;
                float t1 = ps + row_shr<1>(ps);
                float s8 = t1 + row_shr<2>(t1);      // pairs k-3..k
                float eL = row_shr<3>(cf[f].x);      // col 2k-6
                sv[f].x = s8 - cf[f].y;              // cols 2k-6..2k (even)
                sv[f].y = s8 - eL;                   // cols 2k-5..2k+1 (odd)
            }
        }

        // ---- temporal 7-ring (slot jj = s % 7), packed (E,O) ----
#pragma unroll
        for (int f = 0; f < 4; ++f) {
            tEO[f] += sv[f] - rEO[f][jj];
            rEO[f][jj] = sv[f];
        }

        // ---- SSIM on packed (E,O), emit for t_out = s - 6 ----
        if (doEmit) {
            v2f ux  = tEO[0] * invv;
            v2f uy  = tEO[1] * invv;
            v2f u2  = tEO[2] * invv;
            v2f uxy = tEO[3] * invv;
            v2f m   = __builtin_elementwise_fma(-ux, uy, uxy);
            v2f A2  = __builtin_elementwise_fma(c2cov, m, C2vv);
            v2f nb  = __builtin_elementwise_fma(-ux, ux, u2);
            nb      = __builtin_elementwise_fma(-uy, uy, nb);
            v2f B2  = __builtin_elementwise_fma(covnv, nb, C2vv);
            v2f ux2 = ux + ux;
            v2f A1  = __builtin_elementwise_fma(ux2, uy, C1vv);
            v2f B1  = __builtin_elementwise_fma(
                          ux, ux, __builtin_elementwise_fma(uy, uy, C1vv));
            v2f num = A1 * A2;
            v2f den = B1 * B2;
            float sx = __fdividef(num.x, den.x);
            float sy = __fdividef(num.y, den.y);
            if (vE) loss += 1.f - sx;
            if (vO) loss += 1.f - sy;
        }
    };

    // ---- prologue (wave-local, no barrier) ----
    loadw(0);
    commitw(0);
    loadw(1);

    // slices 0..6: ring fill, emit only at s==6
#pragma unroll
    for (int jj = 0; jj < 7; ++jj)
        slice(jj, jj, jj == 6, true, true);

    // slices 7..27: fully unconditional (s+2 <= 29 < 32)
    for (int a = 7; a <= 21; a += 7)
#pragma unroll
        for (int jj = 0; jj < 7; ++jj)
            slice(a + jj, jj, true, true, true);

    // tail: s = 28..31 (flags compile-time)
    slice(28, 0, true, true, true);    // commit 29, load 30
    slice(29, 1, true, true, true);    // commit 30, load 31
    slice(30, 2, true, true, false);   // commit 31
    slice(31, 3, true, false, false);

    // ---- block reduction -> global atomic (single barrier) ----
    for (int off = 32; off > 0; off >>= 1)
        loss += __shfl_down(loss, off, 64);
    if (lane == 0) wsum[wv] = loss;
    __syncthreads();
    if (tid == 0) {
        float s = wsum[0] + wsum[1] + wsum[2] + wsum[3];
        atomicAdd(acc, (double)s);
    }
}

__global__ void ssim3d_finalize(const double* __restrict__ acc,
                                float* __restrict__ out)
{
    out[0] = (float)(acc[0] / (double)NOUT);
}

extern "C" void kernel_launch(void* const* d_in, const int* in_sizes, int n_in,
                              void* d_out, int out_size, void* d_ws, size_t ws_size,
                              hipStream_t stream)
{
    const float* pred   = (const float*)d_in[0];
    const float* targ   = (const float*)d_in[1];
    const float* drange = (const float*)d_in[2];
    float* out  = (float*)d_out;
    double* acc = (double*)d_ws;

    hipMemsetAsync(acc, 0, sizeof(double), stream);

    const int nblocks = B * NTH * NTW;  // 1040
    ssim3d_fused<<<nblocks, 256, 0, stream>>>(pred, targ, drange, acc);
    ssim3d_finalize<<<1, 1, 0, stream>>>(acc, out);
}